// Round 2
// baseline (318.638 us; speedup 1.0000x reference)
//
#include <hip/hip_runtime.h>
#include <cstdint>
#include <cstddef>

// ForwardAttention: B=32, T=2048, Q=K=V=512, A=128, TEMP=1
// d_out = [context 32x512 | fw 32x2048] f32  (81920 floats)
//
// Pipeline (v3: barrier-free register-resident energy GEMM):
//  1) prep:      qp = query@Wq (fp32), WkT = bf16(Wk^T) [128][512]        -> ws
//  2) energy:    bf16 MFMA GEMM keys@Wk, NO LDS / NO barriers: per-wave
//                32x128 strip, A fp32->bf16 packed in-register, B frags
//                loaded from L1/L2-resident WkT. Fused tanh/We epilogue.  -> ws energy
//  3) ctx_fused: per (b,t-chunk) block: values preloaded (issue-early),
//                replicated masked softmax + forward reweight in LDS,
//                own fw chunk to d_out, context partial over own chunk    -> ws part
//  4) ctx_reduce: sum partials -> context region of d_out

#define T_ 2048
#define KD 512
#define AD 128

typedef __attribute__((ext_vector_type(8))) short bf16x8;
typedef __attribute__((ext_vector_type(4))) float f32x4;

__device__ __forceinline__ unsigned pack2bf(float a, float b) {
    unsigned ua = __float_as_uint(a), ub = __float_as_uint(b);
    ua += 0x7FFFu + ((ua >> 16) & 1u);   // RNE
    ub += 0x7FFFu + ((ub >> 16) & 1u);
    return (ua >> 16) | (ub & 0xFFFF0000u);
}

// ---------------- kernel 1: qp + WkT(bf16) prep ----------------
__global__ __launch_bounds__(256) void prep_kernel(
    const float* __restrict__ query, const float* __restrict__ Wq,
    const float* __restrict__ Wk, float* __restrict__ qp,
    unsigned short* __restrict__ WkT)
{
    __shared__ float sq[128];
    const int tid = threadIdx.x;
    if (blockIdx.x < 32) {
        // qp[b][a] = sum_k query[b][k] * Wq[k][a], fp32 exact
        const int b = blockIdx.x;
        const int a = tid & 127, half = tid >> 7;
        const float* q = query + (size_t)b * KD + half * 256;
        const float* w = Wq + (size_t)(half * 256) * AD + a;
        float s0 = 0.f, s1 = 0.f, s2 = 0.f, s3 = 0.f;
        #pragma unroll 4
        for (int k = 0; k < 256; k += 4) {
            s0 += q[k + 0] * w[(size_t)(k + 0) * AD];
            s1 += q[k + 1] * w[(size_t)(k + 1) * AD];
            s2 += q[k + 2] * w[(size_t)(k + 2) * AD];
            s3 += q[k + 3] * w[(size_t)(k + 3) * AD];
        }
        float s = (s0 + s1) + (s2 + s3);
        if (half == 0) sq[a] = s;
        __syncthreads();
        if (half == 1) qp[(size_t)b * AD + a] = sq[a] + s;
    } else {
        // WkT[n][k] = bf16(Wk[k][n]); coalesced reads of Wk rows
        const int blk2 = blockIdx.x - 32;      // 0..31, 16 k-rows each
        const int n = tid & 127, kr = tid >> 7;
        #pragma unroll
        for (int kk = 0; kk < 8; kk++) {
            int k = blk2 * 16 + kr * 8 + kk;
            float v = Wk[(size_t)k * AD + n];
            unsigned u = __float_as_uint(v);
            u += 0x7FFFu + ((u >> 16) & 1u);
            WkT[(size_t)n * KD + k] = (unsigned short)(u >> 16);
        }
    }
}

// ---------------- kernel 2: energies via bf16 MFMA (barrier-free) ----------------
// Global GEMM: M=65536 (b*2048+t), K=512, N=128. Per-wave 32x128 strip.
// A fragment: lane(lr,quad) holds keys[m][k0+quad*8 .. +8] (8 fp32 -> bf16x8),
//   identical bit pattern to the v2 LDS-staged path -> bit-identical energies.
// B fragment: lane(lr,quad) holds WkT[nt*16+lr][k0+quad*8 .. +8] (16B load);
//   same addresses wave-to-wave -> L1 broadcast, ~zero HBM.
// No LDS, no __syncthreads -> no vmcnt(0) drain points; keys stream freely.
// Epilogue: energy[m] = sum_a We[a]*tanh(kp[m][a] + qp[b][a])
__global__ __launch_bounds__(256) void energy_kernel(
    const float* __restrict__ keys, const unsigned short* __restrict__ WkT,
    const float* __restrict__ qp, const float* __restrict__ We,
    float* __restrict__ energy)
{
    const int tid = threadIdx.x;
    const int lane = tid & 63, wv = tid >> 6;
    const int lr = lane & 15, quad = lane >> 4;
    const int m0 = blockIdx.x * 128 + wv * 32;     // wave's first row
    const int b = (blockIdx.x * 128) >> 11;        // 16 blocks/batch

    const float* gA0 = keys + (size_t)(m0 + lr) * KD + quad * 8;
    const float* gA1 = keys + (size_t)(m0 + 16 + lr) * KD + quad * 8;
    const unsigned short* gB = WkT + (size_t)lr * KD + quad * 8;

    f32x4 acc[2][8];
    #pragma unroll
    for (int mt = 0; mt < 2; mt++)
        #pragma unroll
        for (int nt = 0; nt < 8; nt++)
            acc[mt][nt] = (f32x4){0.f, 0.f, 0.f, 0.f};

    #pragma unroll 2
    for (int k0 = 0; k0 < KD; k0 += 32) {
        // B fragments (L1-resident after first wave touches them)
        uint4 braw[8];
        #pragma unroll
        for (int nt = 0; nt < 8; nt++)
            braw[nt] = *(const uint4*)(gB + (size_t)(nt * 16) * KD + k0);
        // A fragments: 8 consecutive fp32 per lane, pack to bf16 (RNE)
        float4 a00 = *(const float4*)(gA0 + k0);
        float4 a01 = *(const float4*)(gA0 + k0 + 4);
        float4 a10 = *(const float4*)(gA1 + k0);
        float4 a11 = *(const float4*)(gA1 + k0 + 4);
        uint4 p0, p1;
        p0.x = pack2bf(a00.x, a00.y); p0.y = pack2bf(a00.z, a00.w);
        p0.z = pack2bf(a01.x, a01.y); p0.w = pack2bf(a01.z, a01.w);
        p1.x = pack2bf(a10.x, a10.y); p1.y = pack2bf(a10.z, a10.w);
        p1.z = pack2bf(a11.x, a11.y); p1.w = pack2bf(a11.z, a11.w);
        bf16x8 af0, af1;
        __builtin_memcpy(&af0, &p0, 16);
        __builtin_memcpy(&af1, &p1, 16);
        #pragma unroll
        for (int nt = 0; nt < 8; nt++) {
            bf16x8 bf;
            __builtin_memcpy(&bf, &braw[nt], 16);
            acc[0][nt] = __builtin_amdgcn_mfma_f32_16x16x32_bf16(af0, bf, acc[0][nt], 0, 0, 0);
            acc[1][nt] = __builtin_amdgcn_mfma_f32_16x16x32_bf16(af1, bf, acc[1][nt], 0, 0, 0);
        }
    }

    // epilogue: tanh + We-weighted row reduction (identical order to v2)
    float part[2][4] = {{0.f, 0.f, 0.f, 0.f}, {0.f, 0.f, 0.f, 0.f}};
    #pragma unroll
    for (int nt = 0; nt < 8; nt++) {
        int col = nt * 16 + lr;
        float we = We[col];
        float q  = qp[(size_t)b * AD + col];
        #pragma unroll
        for (int mt = 0; mt < 2; mt++)
            #pragma unroll
            for (int r = 0; r < 4; r++) {
                float x = acc[mt][nt][r] + q;
                float e2 = __expf(2.0f * x);        // tanh(x)=1-2/(e^{2x}+1)
                float th = 1.0f - 2.0f / (e2 + 1.0f);
                part[mt][r] += we * th;
            }
    }
    #pragma unroll
    for (int mt = 0; mt < 2; mt++)
        #pragma unroll
        for (int r = 0; r < 4; r++) {
            float v = part[mt][r];
            v += __shfl_xor(v, 1); v += __shfl_xor(v, 2);
            v += __shfl_xor(v, 4); v += __shfl_xor(v, 8);
            if (lr == 0)
                energy[(size_t)m0 + mt * 16 + quad * 4 + r] = v;
        }
}

// ---------------- block reductions (identical order to v1) ----------------
__device__ __forceinline__ float block_red_max(float v, float* sred) {
    #pragma unroll
    for (int m = 1; m < 64; m <<= 1) v = fmaxf(v, __shfl_xor(v, m));
    if ((threadIdx.x & 63) == 0) sred[threadIdx.x >> 6] = v;
    __syncthreads();
    float r = fmaxf(fmaxf(sred[0], sred[1]), fmaxf(sred[2], sred[3]));
    __syncthreads();
    return r;
}
__device__ __forceinline__ float block_red_sum(float v, float* sred) {
    #pragma unroll
    for (int m = 1; m < 64; m <<= 1) v += __shfl_xor(v, m);
    if ((threadIdx.x & 63) == 0) sred[threadIdx.x >> 6] = v;
    __syncthreads();
    float r = (sred[0] + sred[1]) + (sred[2] + sred[3]);
    __syncthreads();
    return r;
}

// ---------------- kernel 3: fused softmax + forward attn + context partial ----
// Grid 512 = 32 batches x 16 t-chunks. Every block for batch b redundantly
// recomputes the softmax/forward-reweight stats for the full T=2048 row in the
// EXACT reduction order of the v1 softmax kernel (bit-identical fw), writes
// its own 128-wide fw chunk to d_out, then accumulates its context partial.
// v3: first 8 values-float4 per thread are issued at kernel entry so the
// 134 MB values stream overlaps the softmax prologue (issue-early).
__global__ __launch_bounds__(256) void ctx_fused_kernel(
    const float* __restrict__ energy, const float* __restrict__ prev,
    const int* __restrict__ mask, const float* __restrict__ values,
    float* __restrict__ fw, float* __restrict__ part)
{
    __shared__ float sred[4];
    __shared__ float sfw[2048];
    __shared__ float4 sacc[128];
    const int b = blockIdx.x >> 4, ts = blockIdx.x & 15;
    const int tid = threadIdx.x;
    const size_t base = (size_t)b * T_;
    const int t0 = ts * 128;

    // issue-early: first 8 values loads (cover softmax-prologue latency)
    const int d4 = tid & 127, tp = tid >> 7;
    const float4* vp = (const float4*)values + ((size_t)b * T_ + t0 + tp) * 128 + d4;
    float4 pre[8];
    #pragma unroll
    for (int i = 0; i < 8; i++) pre[i] = vp[(size_t)i * 256];

    // ---- replicated masked softmax (same order as v1 softmax kernel) ----
    float e[8];
    #pragma unroll
    for (int i = 0; i < 8; i++) {
        int t = tid + 256 * i;
        float ev = energy[base + t];
        if (mask[base + t] == 0) ev = -__builtin_inff();
        e[i] = ev;
    }
    float mx = e[0];
    #pragma unroll
    for (int i = 1; i < 8; i++) mx = fmaxf(mx, e[i]);
    mx = block_red_max(mx, sred);

    float ex[8]; float s = 0.f;
    #pragma unroll
    for (int i = 0; i < 8; i++) { ex[i] = __expf(e[i] - mx); s += ex[i]; }
    s = block_red_sum(s, sred);
    const float invS = 1.0f / s;

    float fwv[8]; float s2 = 0.f;
    #pragma unroll
    for (int i = 0; i < 8; i++) {
        int t = tid + 256 * i;
        float pv = prev[base + t];
        float pm = (t == 0) ? 0.f : prev[base + t - 1];
        float r = ex[i] * invS;
        fwv[i] = (t == 0) ? r : r * (pv + pm);
        s2 += fwv[i];
    }
    s2 = block_red_sum(s2, sred);
    const float invD = 1.0f / (s2 + 1e-8f);
    #pragma unroll
    for (int i = 0; i < 8; i++)
        sfw[tid + 256 * i] = fwv[i] * invD;
    __syncthreads();

    // own-chunk fw writeback (each chunk written exactly once across grid)
    if (tid < 128) fw[base + t0 + tid] = sfw[t0 + tid];

    // ---- context partial over own chunk (FMA order identical to v2) ----
    const float* sf = &sfw[t0];
    float4 acc = {0.f, 0.f, 0.f, 0.f};
    #pragma unroll
    for (int i = 0; i < 8; i++) {
        float f = sf[tp + 2 * i];
        float4 v = pre[i];
        acc.x += f * v.x; acc.y += f * v.y; acc.z += f * v.z; acc.w += f * v.w;
    }
    #pragma unroll 8
    for (int i = 8; i < 64; i++) {
        float f = sf[tp + 2 * i];
        float4 v = vp[(size_t)i * 256];
        acc.x += f * v.x; acc.y += f * v.y; acc.z += f * v.z; acc.w += f * v.w;
    }
    if (tp) sacc[d4] = acc;
    __syncthreads();
    if (!tp) {
        float4 o = sacc[d4];
        o.x += acc.x; o.y += acc.y; o.z += acc.z; o.w += acc.w;
        ((float4*)part)[(size_t)blockIdx.x * 128 + d4] = o;
    }
}

// ---------------- kernel 4: reduce partials -> context ----------------
__global__ __launch_bounds__(256) void ctx_reduce_kernel(
    const float* __restrict__ part, float* __restrict__ ctx)
{
    const int idx = blockIdx.x * 256 + threadIdx.x;  // 0..16383
    const int b = idx >> 9, d = idx & 511;
    float s = 0.f;
    #pragma unroll
    for (int ts = 0; ts < 16; ts++)
        s += part[((size_t)(b * 16 + ts)) * 512 + d];
    ctx[idx] = s;
}

extern "C" void kernel_launch(void* const* d_in, const int* in_sizes, int n_in,
                              void* d_out, int out_size, void* d_ws, size_t ws_size,
                              hipStream_t stream) {
    const float* query  = (const float*)d_in[0];
    const float* keys   = (const float*)d_in[1];
    const float* values = (const float*)d_in[2];
    const float* prev   = (const float*)d_in[3];
    const int*   mask   = (const int*)d_in[4];
    const float* Wq     = (const float*)d_in[5];
    const float* Wk     = (const float*)d_in[6];
    const float* We     = (const float*)d_in[7];

    float* ctx = (float*)d_out;          // 32*512
    float* fw  = ctx + 32 * 512;         // 32*2048 (final fw only; energies in ws)

    float* wsf = (float*)d_ws;
    float* qp     = wsf;                                  // 4096 floats
    float* part   = wsf + 4096;                           // 16*32*512 = 262144 floats
    float* energy = wsf + 4096 + 262144;                  // 65536 floats
    unsigned short* WkT = (unsigned short*)(wsf + 4096 + 262144 + 65536);  // 65536 ushorts

    prep_kernel<<<dim3(64), dim3(256), 0, stream>>>(query, Wq, Wk, qp, WkT);
    energy_kernel<<<dim3(512), dim3(256), 0, stream>>>(keys, WkT, qp, We, energy);
    ctx_fused_kernel<<<dim3(512), dim3(256), 0, stream>>>(energy, prev, mask, values, fw, part);
    ctx_reduce_kernel<<<dim3(64), dim3(256), 0, stream>>>(part, ctx);
}

// Round 3
// 308.325 us; speedup vs baseline: 1.0334x; 1.0334x over previous
//
#include <hip/hip_runtime.h>
#include <cstdint>
#include <cstddef>

// ForwardAttention: B=32, T=2048, Q=K=V=512, A=128, TEMP=1
// d_out = [context 32x512 | fw 32x2048] f32  (81920 floats)
//
// Pipeline (v4: v2 structure + double-buffered energy GEMM):
//  1) prep:      qp = query@Wq (fp32), WkT = bf16(Wk^T) [128][512]        -> ws
//  2) energy:    bf16 MFMA GEMM keys@Wk, LDS DOUBLE-buffered 2-phase:
//                issue loads(t+1) -> MFMA on buf[cur] -> pack+ds_write(t+1)
//                -> ONE barrier. HBM latency hides under MFMA phase.      -> ws energy
//  3) ctx_fused: per (b,t-chunk) block: values preloaded (issue-early),
//                replicated masked softmax + forward reweight in LDS,
//                own fw chunk to d_out, context partial over own chunk    -> ws part
//  4) ctx_reduce: sum partials -> context region of d_out

#define T_ 2048
#define KD 512
#define AD 128

typedef __attribute__((ext_vector_type(8))) short bf16x8;
typedef __attribute__((ext_vector_type(4))) float f32x4;

__device__ __forceinline__ unsigned pack2bf(float a, float b) {
    unsigned ua = __float_as_uint(a), ub = __float_as_uint(b);
    ua += 0x7FFFu + ((ua >> 16) & 1u);   // RNE
    ub += 0x7FFFu + ((ub >> 16) & 1u);
    return (ua >> 16) | (ub & 0xFFFF0000u);
}

// ---------------- kernel 1: qp + WkT(bf16) prep ----------------
__global__ __launch_bounds__(256) void prep_kernel(
    const float* __restrict__ query, const float* __restrict__ Wq,
    const float* __restrict__ Wk, float* __restrict__ qp,
    unsigned short* __restrict__ WkT)
{
    __shared__ float sq[128];
    const int tid = threadIdx.x;
    if (blockIdx.x < 32) {
        // qp[b][a] = sum_k query[b][k] * Wq[k][a], fp32 exact
        const int b = blockIdx.x;
        const int a = tid & 127, half = tid >> 7;
        const float* q = query + (size_t)b * KD + half * 256;
        const float* w = Wq + (size_t)(half * 256) * AD + a;
        float s0 = 0.f, s1 = 0.f, s2 = 0.f, s3 = 0.f;
        #pragma unroll 4
        for (int k = 0; k < 256; k += 4) {
            s0 += q[k + 0] * w[(size_t)(k + 0) * AD];
            s1 += q[k + 1] * w[(size_t)(k + 1) * AD];
            s2 += q[k + 2] * w[(size_t)(k + 2) * AD];
            s3 += q[k + 3] * w[(size_t)(k + 3) * AD];
        }
        float s = (s0 + s1) + (s2 + s3);
        if (half == 0) sq[a] = s;
        __syncthreads();
        if (half == 1) qp[(size_t)b * AD + a] = sq[a] + s;
    } else {
        // WkT[n][k] = bf16(Wk[k][n]); coalesced reads of Wk rows
        const int blk2 = blockIdx.x - 32;      // 0..31, 16 k-rows each
        const int n = tid & 127, kr = tid >> 7;
        #pragma unroll
        for (int kk = 0; kk < 8; kk++) {
            int k = blk2 * 16 + kr * 8 + kk;
            float v = Wk[(size_t)k * AD + n];
            unsigned u = __float_as_uint(v);
            u += 0x7FFFu + ((u >> 16) & 1u);
            WkT[(size_t)n * KD + k] = (unsigned short)(u >> 16);
        }
    }
}

// ---------------- kernel 2: energies via bf16 MFMA (double-buffered) ------
// Global GEMM: M=65536 (b*2048+t), K=512, N=128. Block: BM=128, BK=32, full N.
// Per K-step: issue global loads for step t+1 -> ds_read+MFMA on buf[cur]
// (hides ~900cy HBM latency) -> pack+ds_write into buf[cur^1] -> ONE barrier.
// Invariant: at step entry, buf[cur] is fully written (t-1's writes behind the
// barrier) and buf[cur^1] is free (all its reads happened in t-1).
// Fragment contents / MFMA order / epilogue identical to v2 -> bit-identical.
__global__ __launch_bounds__(256, 2) void energy_kernel(
    const float* __restrict__ keys, const unsigned short* __restrict__ WkT,
    const float* __restrict__ qp, const float* __restrict__ We,
    float* __restrict__ energy)
{
    __shared__ __align__(16) unsigned short sA[2][128 * 40];  // [m][k], pad->40
    __shared__ __align__(16) unsigned short sB[2][128 * 40];  // [n][k], pad->40
    const int tid = threadIdx.x;
    const int m0 = blockIdx.x * 128;
    const int b = m0 >> 11;

    const int row = tid >> 1, half = tid & 1;   // staging: 2 threads/row, 16 elems each
    const float* gA = keys + (size_t)(m0 + row) * KD + half * 16;
    const unsigned short* gB = WkT + (size_t)row * KD + half * 16;
    const int doff = row * 40 + half * 16;

    const int lane = tid & 63, wv = tid >> 6;
    const int lr = lane & 15, quad = lane >> 4;

    f32x4 acc[2][8];
    #pragma unroll
    for (int mt = 0; mt < 2; mt++)
        #pragma unroll
        for (int nt = 0; nt < 8; nt++)
            acc[mt][nt] = (f32x4){0.f, 0.f, 0.f, 0.f};

    // ---- prologue: stage k0=0 into buf 0 ----
    {
        float4 f0 = *(const float4*)(gA + 0);
        float4 f1 = *(const float4*)(gA + 4);
        float4 f2 = *(const float4*)(gA + 8);
        float4 f3 = *(const float4*)(gA + 12);
        uint4 b0 = *(const uint4*)(gB + 0);
        uint4 b1 = *(const uint4*)(gB + 8);
        uint4 pa0, pa1;
        pa0.x = pack2bf(f0.x, f0.y); pa0.y = pack2bf(f0.z, f0.w);
        pa0.z = pack2bf(f1.x, f1.y); pa0.w = pack2bf(f1.z, f1.w);
        pa1.x = pack2bf(f2.x, f2.y); pa1.y = pack2bf(f2.z, f2.w);
        pa1.z = pack2bf(f3.x, f3.y); pa1.w = pack2bf(f3.z, f3.w);
        ((uint4*)&sA[0][doff])[0] = pa0; ((uint4*)&sA[0][doff])[1] = pa1;
        ((uint4*)&sB[0][doff])[0] = b0;  ((uint4*)&sB[0][doff])[1] = b1;
    }
    __syncthreads();

    int cur = 0;
    for (int k0 = 0; k0 < KD; k0 += 32) {
        const int kn = k0 + 32;
        const bool has_next = kn < KD;
        // ---- issue next tile's global loads FIRST (latency hides under MFMA)
        float4 f0, f1, f2, f3; uint4 bb0, bb1;
        if (has_next) {
            f0 = *(const float4*)(gA + kn + 0);
            f1 = *(const float4*)(gA + kn + 4);
            f2 = *(const float4*)(gA + kn + 8);
            f3 = *(const float4*)(gA + kn + 12);
            bb0 = *(const uint4*)(gB + kn);
            bb1 = *(const uint4*)(gB + kn + 8);
        }
        // ---- compute on buf[cur] ----
        bf16x8 af[2], bfm[8];
        #pragma unroll
        for (int mt = 0; mt < 2; mt++)
            af[mt] = *(const bf16x8*)&sA[cur][(wv * 32 + mt * 16 + lr) * 40 + quad * 8];
        #pragma unroll
        for (int nt = 0; nt < 8; nt++)
            bfm[nt] = *(const bf16x8*)&sB[cur][(nt * 16 + lr) * 40 + quad * 8];
        #pragma unroll
        for (int mt = 0; mt < 2; mt++)
            #pragma unroll
            for (int nt = 0; nt < 8; nt++)
                acc[mt][nt] = __builtin_amdgcn_mfma_f32_16x16x32_bf16(
                    af[mt], bfm[nt], acc[mt][nt], 0, 0, 0);
        // ---- pack + write next tile into buf[cur^1] (write-late) ----
        if (has_next) {
            uint4 pa0, pa1;
            pa0.x = pack2bf(f0.x, f0.y); pa0.y = pack2bf(f0.z, f0.w);
            pa0.z = pack2bf(f1.x, f1.y); pa0.w = pack2bf(f1.z, f1.w);
            pa1.x = pack2bf(f2.x, f2.y); pa1.y = pack2bf(f2.z, f2.w);
            pa1.z = pack2bf(f3.x, f3.y); pa1.w = pack2bf(f3.z, f3.w);
            ((uint4*)&sA[cur ^ 1][doff])[0] = pa0; ((uint4*)&sA[cur ^ 1][doff])[1] = pa1;
            ((uint4*)&sB[cur ^ 1][doff])[0] = bb0; ((uint4*)&sB[cur ^ 1][doff])[1] = bb1;
        }
        __syncthreads();
        cur ^= 1;
    }

    // epilogue: tanh + We-weighted row reduction (identical order to v2)
    float part[2][4] = {{0.f, 0.f, 0.f, 0.f}, {0.f, 0.f, 0.f, 0.f}};
    #pragma unroll
    for (int nt = 0; nt < 8; nt++) {
        int col = nt * 16 + lr;
        float we = We[col];
        float q  = qp[(size_t)b * AD + col];
        #pragma unroll
        for (int mt = 0; mt < 2; mt++)
            #pragma unroll
            for (int r = 0; r < 4; r++) {
                float x = acc[mt][nt][r] + q;
                float e2 = __expf(2.0f * x);        // tanh(x)=1-2/(e^{2x}+1)
                float th = 1.0f - 2.0f / (e2 + 1.0f);
                part[mt][r] += we * th;
            }
    }
    #pragma unroll
    for (int mt = 0; mt < 2; mt++)
        #pragma unroll
        for (int r = 0; r < 4; r++) {
            float v = part[mt][r];
            v += __shfl_xor(v, 1); v += __shfl_xor(v, 2);
            v += __shfl_xor(v, 4); v += __shfl_xor(v, 8);
            if (lr == 0)
                energy[(size_t)m0 + wv * 32 + mt * 16 + quad * 4 + r] = v;
        }
}

// ---------------- block reductions (identical order to v1) ----------------
__device__ __forceinline__ float block_red_max(float v, float* sred) {
    #pragma unroll
    for (int m = 1; m < 64; m <<= 1) v = fmaxf(v, __shfl_xor(v, m));
    if ((threadIdx.x & 63) == 0) sred[threadIdx.x >> 6] = v;
    __syncthreads();
    float r = fmaxf(fmaxf(sred[0], sred[1]), fmaxf(sred[2], sred[3]));
    __syncthreads();
    return r;
}
__device__ __forceinline__ float block_red_sum(float v, float* sred) {
    #pragma unroll
    for (int m = 1; m < 64; m <<= 1) v += __shfl_xor(v, m);
    if ((threadIdx.x & 63) == 0) sred[threadIdx.x >> 6] = v;
    __syncthreads();
    float r = (sred[0] + sred[1]) + (sred[2] + sred[3]);
    __syncthreads();
    return r;
}

// ---------------- kernel 3: fused softmax + forward attn + context partial ----
// Grid 512 = 32 batches x 16 t-chunks. Every block for batch b redundantly
// recomputes the softmax/forward-reweight stats for the full T=2048 row in the
// EXACT reduction order of the v1 softmax kernel (bit-identical fw), writes
// its own 128-wide fw chunk to d_out, then accumulates its context partial.
// First 8 values-float4 per thread are issued at kernel entry so the 134 MB
// values stream overlaps the softmax prologue (issue-early, T14).
__global__ __launch_bounds__(256) void ctx_fused_kernel(
    const float* __restrict__ energy, const float* __restrict__ prev,
    const int* __restrict__ mask, const float* __restrict__ values,
    float* __restrict__ fw, float* __restrict__ part)
{
    __shared__ float sred[4];
    __shared__ float sfw[2048];
    __shared__ float4 sacc[128];
    const int b = blockIdx.x >> 4, ts = blockIdx.x & 15;
    const int tid = threadIdx.x;
    const size_t base = (size_t)b * T_;
    const int t0 = ts * 128;

    // issue-early: first 8 values loads (cover softmax-prologue latency)
    const int d4 = tid & 127, tp = tid >> 7;
    const float4* vp = (const float4*)values + ((size_t)b * T_ + t0 + tp) * 128 + d4;
    float4 pre[8];
    #pragma unroll
    for (int i = 0; i < 8; i++) pre[i] = vp[(size_t)i * 256];

    // ---- replicated masked softmax (same order as v1 softmax kernel) ----
    float e[8];
    #pragma unroll
    for (int i = 0; i < 8; i++) {
        int t = tid + 256 * i;
        float ev = energy[base + t];
        if (mask[base + t] == 0) ev = -__builtin_inff();
        e[i] = ev;
    }
    float mx = e[0];
    #pragma unroll
    for (int i = 1; i < 8; i++) mx = fmaxf(mx, e[i]);
    mx = block_red_max(mx, sred);

    float ex[8]; float s = 0.f;
    #pragma unroll
    for (int i = 0; i < 8; i++) { ex[i] = __expf(e[i] - mx); s += ex[i]; }
    s = block_red_sum(s, sred);
    const float invS = 1.0f / s;

    float fwv[8]; float s2 = 0.f;
    #pragma unroll
    for (int i = 0; i < 8; i++) {
        int t = tid + 256 * i;
        float pv = prev[base + t];
        float pm = (t == 0) ? 0.f : prev[base + t - 1];
        float r = ex[i] * invS;
        fwv[i] = (t == 0) ? r : r * (pv + pm);
        s2 += fwv[i];
    }
    s2 = block_red_sum(s2, sred);
    const float invD = 1.0f / (s2 + 1e-8f);
    #pragma unroll
    for (int i = 0; i < 8; i++)
        sfw[tid + 256 * i] = fwv[i] * invD;
    __syncthreads();

    // own-chunk fw writeback (each chunk written exactly once across grid)
    if (tid < 128) fw[base + t0 + tid] = sfw[t0 + tid];

    // ---- context partial over own chunk (FMA order identical to v2) ----
    const float* sf = &sfw[t0];
    float4 acc = {0.f, 0.f, 0.f, 0.f};
    #pragma unroll
    for (int i = 0; i < 8; i++) {
        float f = sf[tp + 2 * i];
        float4 v = pre[i];
        acc.x += f * v.x; acc.y += f * v.y; acc.z += f * v.z; acc.w += f * v.w;
    }
    #pragma unroll 8
    for (int i = 8; i < 64; i++) {
        float f = sf[tp + 2 * i];
        float4 v = vp[(size_t)i * 256];
        acc.x += f * v.x; acc.y += f * v.y; acc.z += f * v.z; acc.w += f * v.w;
    }
    if (tp) sacc[d4] = acc;
    __syncthreads();
    if (!tp) {
        float4 o = sacc[d4];
        o.x += acc.x; o.y += acc.y; o.z += acc.z; o.w += acc.w;
        ((float4*)part)[(size_t)blockIdx.x * 128 + d4] = o;
    }
}

// ---------------- kernel 4: reduce partials -> context ----------------
__global__ __launch_bounds__(256) void ctx_reduce_kernel(
    const float* __restrict__ part, float* __restrict__ ctx)
{
    const int idx = blockIdx.x * 256 + threadIdx.x;  // 0..16383
    const int b = idx >> 9, d = idx & 511;
    float s = 0.f;
    #pragma unroll
    for (int ts = 0; ts < 16; ts++)
        s += part[((size_t)(b * 16 + ts)) * 512 + d];
    ctx[idx] = s;
}

extern "C" void kernel_launch(void* const* d_in, const int* in_sizes, int n_in,
                              void* d_out, int out_size, void* d_ws, size_t ws_size,
                              hipStream_t stream) {
    const float* query  = (const float*)d_in[0];
    const float* keys   = (const float*)d_in[1];
    const float* values = (const float*)d_in[2];
    const float* prev   = (const float*)d_in[3];
    const int*   mask   = (const int*)d_in[4];
    const float* Wq     = (const float*)d_in[5];
    const float* Wk     = (const float*)d_in[6];
    const float* We     = (const float*)d_in[7];

    float* ctx = (float*)d_out;          // 32*512
    float* fw  = ctx + 32 * 512;         // 32*2048 (final fw only; energies in ws)

    float* wsf = (float*)d_ws;
    float* qp     = wsf;                                  // 4096 floats
    float* part   = wsf + 4096;                           // 16*32*512 = 262144 floats
    float* energy = wsf + 4096 + 262144;                  // 65536 floats
    unsigned short* WkT = (unsigned short*)(wsf + 4096 + 262144 + 65536);  // 65536 ushorts

    prep_kernel<<<dim3(64), dim3(256), 0, stream>>>(query, Wq, Wk, qp, WkT);
    energy_kernel<<<dim3(512), dim3(256), 0, stream>>>(keys, WkT, qp, We, energy);
    ctx_fused_kernel<<<dim3(512), dim3(256), 0, stream>>>(energy, prev, mask, values, fw, part);
    ctx_reduce_kernel<<<dim3(64), dim3(256), 0, stream>>>(part, ctx);
}